// Round 1
// baseline (115.598 us; speedup 1.0000x reference)
//
#include <hip/hip_runtime.h>
#include <stdint.h>

// ============================================================================
// MoE collapses exactly to: out = relu(x @ w1) @ w2   (see round-0 analysis)
//   - shared expert weights => both top-2 slots compute identical f(x[s])
//   - g1+g2 normalized to 1 => combine gather returns f(x[s])
//   - capacity = S and count1+count2 <= S => no token dropped
// So: bf16 MFMA GEMM -> relu -> GEMM. Wg is unused.
// ============================================================================

typedef __attribute__((ext_vector_type(4))) float f32x4;
typedef __attribute__((ext_vector_type(8))) short bf16x8;

__device__ __forceinline__ ushort f2bf(float f) {
  uint32_t u = __float_as_uint(f);
  uint32_t r = (u + 0x7FFFu + ((u >> 16) & 1u)) >> 16;  // RNE
  return (ushort)r;
}

// ---- elementwise fp32 -> bf16, 4 elems/thread -------------------------------
__global__ void cvt4(const float* __restrict__ in, ushort* __restrict__ out, int n4) {
  int i = blockIdx.x * blockDim.x + threadIdx.x;
  if (i >= n4) return;
  float4 v = ((const float4*)in)[i];
  ushort4 o;
  o.x = f2bf(v.x); o.y = f2bf(v.y); o.z = f2bf(v.z); o.w = f2bf(v.w);
  ((ushort4*)out)[i] = o;
}

// ---- transpose + convert: in [R][C] fp32 -> out [C][R] bf16 -----------------
__global__ void transpose_cvt(const float* __restrict__ in, ushort* __restrict__ out,
                              int R, int C) {
  __shared__ float tile[32][33];
  const int c0 = blockIdx.x * 32, r0 = blockIdx.y * 32;
  const int tx = threadIdx.x, ty = threadIdx.y;  // blockDim (32,8)
#pragma unroll
  for (int i = 0; i < 32; i += 8)
    tile[ty + i][tx] = in[(size_t)(r0 + ty + i) * C + (c0 + tx)];
  __syncthreads();
#pragma unroll
  for (int i = 0; i < 32; i += 8)
    out[(size_t)(c0 + ty + i) * R + (r0 + tx)] = f2bf(tile[tx][ty + i]);
}

// ---- bf16 GEMM, B transposed input ([N][K]), C = A@B (+optional relu->bf16) -
// 4 waves in 2x2 grid, per-wave (BM/2)x(BN/2), 16x16x32 bf16 MFMA, BK=64,
// global_load_lds width-16 staging into linear LDS (m97 structure).
template <int BM, int BN, int DO_RELU>
__global__ __launch_bounds__(256) void gemm_bt(const ushort* __restrict__ A,
                                               const ushort* __restrict__ Bt,
                                               void* __restrict__ Cout,
                                               int M, int N, int K) {
  constexpr int BK = 64;
  __shared__ ushort As[BM * BK];
  __shared__ ushort Bs[BN * BK];
  constexpr int MR = BM / 32;  // 16x16 frags per wave along M
  constexpr int NR = BN / 32;
  constexpr int CA = BM / 8;   // 1-KB staging chunks for A tile
  constexpr int CB = BN / 8;
  constexpr int CPW = (CA + CB) / 4;

  const int tid = threadIdx.x;
  const int lane = tid & 63, wid = tid >> 6;
  const int wr = wid >> 1, wc = wid & 1;
  const int row0 = blockIdx.y * BM, col0 = blockIdx.x * BN;

  f32x4 acc[MR][NR];
#pragma unroll
  for (int m = 0; m < MR; ++m)
#pragma unroll
    for (int n = 0; n < NR; ++n) acc[m][n] = (f32x4){0.f, 0.f, 0.f, 0.f};

  for (int k0 = 0; k0 < K; k0 += BK) {
    if (k0) __syncthreads();  // previous compute done before overwriting LDS
#pragma unroll
    for (int i = 0; i < CPW; ++i) {
      int ci = wid * CPW + i;  // wave-uniform chunk id
      if (ci < CA) {
        int e = ci * 512 + lane * 8;       // bf16 element index into As
        int r = e >> 6, c = e & 63;
        __builtin_amdgcn_global_load_lds(
            (const __attribute__((address_space(1))) void*)(A + (size_t)(row0 + r) * K + k0 + c),
            (__attribute__((address_space(3))) void*)(&As[ci * 512]), 16, 0, 0);
      } else {
        int cj = ci - CA;
        int e = cj * 512 + lane * 8;
        int r = e >> 6, c = e & 63;
        __builtin_amdgcn_global_load_lds(
            (const __attribute__((address_space(1))) void*)(Bt + (size_t)(col0 + r) * K + k0 + c),
            (__attribute__((address_space(3))) void*)(&Bs[cj * 512]), 16, 0, 0);
      }
    }
    __syncthreads();  // compiler drains vmcnt before s_barrier

#pragma unroll
    for (int kk = 0; kk < 2; ++kk) {
      const int kb = kk * 32 + (lane >> 4) * 8;
      bf16x8 a[MR], b[NR];
#pragma unroll
      for (int m = 0; m < MR; ++m)
        a[m] = *(const bf16x8*)&As[(wr * (BM / 2) + m * 16 + (lane & 15)) * BK + kb];
#pragma unroll
      for (int n = 0; n < NR; ++n)
        b[n] = *(const bf16x8*)&Bs[(wc * (BN / 2) + n * 16 + (lane & 15)) * BK + kb];
#pragma unroll
      for (int m = 0; m < MR; ++m)
#pragma unroll
        for (int n = 0; n < NR; ++n)
          acc[m][n] = __builtin_amdgcn_mfma_f32_16x16x32_bf16(a[m], b[n], acc[m][n], 0, 0, 0);
    }
  }

  // epilogue; C/D layout (m89-verified): col = lane&15, row = (lane>>4)*4 + j
  const int rbase = row0 + wr * (BM / 2), cbase = col0 + wc * (BN / 2);
#pragma unroll
  for (int m = 0; m < MR; ++m) {
#pragma unroll
    for (int n = 0; n < NR; ++n) {
      const int col = cbase + n * 16 + (lane & 15);
      const int r0q = rbase + m * 16 + ((lane >> 4) << 2);
#pragma unroll
      for (int j = 0; j < 4; ++j) {
        float v = acc[m][n][j];
        if (DO_RELU) {
          v = v > 0.f ? v : 0.f;
          ((ushort*)Cout)[(size_t)(r0q + j) * N + col] = f2bf(v);
        } else {
          ((float*)Cout)[(size_t)(r0q + j) * N + col] = v;
        }
      }
    }
  }
}

extern "C" void kernel_launch(void* const* d_in, const int* in_sizes, int n_in,
                              void* d_out, int out_size, void* d_ws, size_t ws_size,
                              hipStream_t stream) {
  const float* x  = (const float*)d_in[0];
  // d_in[1] (Wg) is provably unused: gating collapses to identity (see header)
  const float* w1 = (const float*)d_in[2];
  const float* w2 = (const float*)d_in[3];
  float* out = (float*)d_out;

  constexpr int S = 2048, D = 1024, F = 4096;
  char* ws = (char*)d_ws;
  ushort* xb  = (ushort*)(ws);                                      // [S][D]  4 MB
  ushort* w1t = (ushort*)(ws + (size_t)S * D * 2);                  // [F][D]  8 MB
  ushort* w2t = (ushort*)(ws + (size_t)(S * D + F * D) * 2);        // [D][F]  8 MB
  ushort* H   = (ushort*)(ws + (size_t)(S * D + 2 * F * D) * 2);    // [S][F] 16 MB

  hipLaunchKernelGGL(cvt4, dim3((S * D / 4 + 255) / 256), dim3(256), 0, stream,
                     x, xb, S * D / 4);
  hipLaunchKernelGGL(transpose_cvt, dim3(F / 32, D / 32), dim3(32, 8), 0, stream,
                     w1, w1t, D, F);
  hipLaunchKernelGGL(transpose_cvt, dim3(D / 32, F / 32), dim3(32, 8), 0, stream,
                     w2, w2t, F, D);
  hipLaunchKernelGGL((gemm_bt<128, 128, 1>), dim3(F / 128, S / 128), dim3(256), 0, stream,
                     xb, w1t, (void*)H, S, F, D);
  hipLaunchKernelGGL((gemm_bt<128, 64, 0>), dim3(D / 64, S / 128), dim3(256), 0, stream,
                     H, w2t, (void*)out, S, D, F);
}

// Round 2
// 97.119 us; speedup vs baseline: 1.1903x; 1.1903x over previous
//
#include <hip/hip_runtime.h>
#include <stdint.h>

// ============================================================================
// MoE collapses exactly to: out = relu(x @ w1) @ w2   (round-0 analysis)
//   - shared expert weights => both top-2 slots compute identical f(x[s])
//   - g1+g2 normalized to 1 => combine gather returns f(x[s])
//   - capacity = S and count1+count2 <= S => no token dropped
// Wg is unused.
//
// Round-1 change: GEMM2 was latency-bound at 1 block/CU (256 blocks,
// MfmaUtil 9%, Occupancy 10.5%). Split-K=2 doubles the grid to 512 blocks
// (2 blocks/CU); z=0 writes d_out, z=1 writes an fp32 partial into ws
// (overlaying dead xb/w1t), then a vectorized out += p1 reduce.
// ============================================================================

typedef __attribute__((ext_vector_type(4))) float f32x4;
typedef __attribute__((ext_vector_type(8))) short bf16x8;

__device__ __forceinline__ ushort f2bf(float f) {
  uint32_t u = __float_as_uint(f);
  uint32_t r = (u + 0x7FFFu + ((u >> 16) & 1u)) >> 16;  // RNE
  return (ushort)r;
}

// ---- elementwise fp32 -> bf16, 4 elems/thread -------------------------------
__global__ void cvt4(const float* __restrict__ in, ushort* __restrict__ out, int n4) {
  int i = blockIdx.x * blockDim.x + threadIdx.x;
  if (i >= n4) return;
  float4 v = ((const float4*)in)[i];
  ushort4 o;
  o.x = f2bf(v.x); o.y = f2bf(v.y); o.z = f2bf(v.z); o.w = f2bf(v.w);
  ((ushort4*)out)[i] = o;
}

// ---- transpose + convert: in [R][C] fp32 -> out [C][R] bf16 -----------------
__global__ void transpose_cvt(const float* __restrict__ in, ushort* __restrict__ out,
                              int R, int C) {
  __shared__ float tile[32][33];
  const int c0 = blockIdx.x * 32, r0 = blockIdx.y * 32;
  const int tx = threadIdx.x, ty = threadIdx.y;  // blockDim (32,8)
#pragma unroll
  for (int i = 0; i < 32; i += 8)
    tile[ty + i][tx] = in[(size_t)(r0 + ty + i) * C + (c0 + tx)];
  __syncthreads();
#pragma unroll
  for (int i = 0; i < 32; i += 8)
    out[(size_t)(c0 + ty + i) * R + (r0 + tx)] = f2bf(tile[tx][ty + i]);
}

// ---- vectorized out += p1 ---------------------------------------------------
__global__ void add_partial(float* __restrict__ out, const float* __restrict__ p1, int n4) {
  int i = blockIdx.x * blockDim.x + threadIdx.x;
  if (i >= n4) return;
  f32x4 a = ((const f32x4*)out)[i];
  f32x4 b = ((const f32x4*)p1)[i];
  ((f32x4*)out)[i] = a + b;
}

// ---- bf16 GEMM, B transposed input ([N][K]), C = A@B (+optional relu->bf16) -
// 4 waves in 2x2 grid, per-wave (BM/2)x(BN/2), 16x16x32 bf16 MFMA, BK=64,
// global_load_lds width-16 staging into linear LDS (m97 structure).
// blockIdx.z selects a K-slice of length Ks and the output buffer (C0/C1).
template <int BM, int BN, int DO_RELU>
__global__ __launch_bounds__(256) void gemm_bt(const ushort* __restrict__ A,
                                               const ushort* __restrict__ Bt,
                                               void* __restrict__ C0,
                                               void* __restrict__ C1,
                                               int M, int N, int Ks, int Ktot) {
  constexpr int BK = 64;
  __shared__ ushort As[BM * BK];
  __shared__ ushort Bs[BN * BK];
  constexpr int MR = BM / 32;  // 16x16 frags per wave along M
  constexpr int NR = BN / 32;
  constexpr int CA = BM / 8;   // 1-KB staging chunks for A tile
  constexpr int CB = BN / 8;
  constexpr int CPW = (CA + CB) / 4;

  const int tid = threadIdx.x;
  const int lane = tid & 63, wid = tid >> 6;
  const int wr = wid >> 1, wc = wid & 1;
  const int row0 = blockIdx.y * BM, col0 = blockIdx.x * BN;
  const int kbase = blockIdx.z * Ks;
  void* Cout = (blockIdx.z == 0) ? C0 : C1;

  f32x4 acc[MR][NR];
#pragma unroll
  for (int m = 0; m < MR; ++m)
#pragma unroll
    for (int n = 0; n < NR; ++n) acc[m][n] = (f32x4){0.f, 0.f, 0.f, 0.f};

  for (int k0 = kbase; k0 < kbase + Ks; k0 += BK) {
    if (k0 != kbase) __syncthreads();  // previous compute done before overwrite
#pragma unroll
    for (int i = 0; i < CPW; ++i) {
      int ci = wid * CPW + i;  // wave-uniform chunk id
      if (ci < CA) {
        int e = ci * 512 + lane * 8;  // bf16 element index into As
        int r = e >> 6, c = e & 63;
        __builtin_amdgcn_global_load_lds(
            (const __attribute__((address_space(1))) void*)(A + (size_t)(row0 + r) * Ktot + k0 + c),
            (__attribute__((address_space(3))) void*)(&As[ci * 512]), 16, 0, 0);
      } else {
        int cj = ci - CA;
        int e = cj * 512 + lane * 8;
        int r = e >> 6, c = e & 63;
        __builtin_amdgcn_global_load_lds(
            (const __attribute__((address_space(1))) void*)(Bt + (size_t)(col0 + r) * Ktot + k0 + c),
            (__attribute__((address_space(3))) void*)(&Bs[cj * 512]), 16, 0, 0);
      }
    }
    __syncthreads();  // compiler drains vmcnt before s_barrier

#pragma unroll
    for (int kk = 0; kk < 2; ++kk) {
      const int kb = kk * 32 + (lane >> 4) * 8;
      bf16x8 a[MR], b[NR];
#pragma unroll
      for (int m = 0; m < MR; ++m)
        a[m] = *(const bf16x8*)&As[(wr * (BM / 2) + m * 16 + (lane & 15)) * BK + kb];
#pragma unroll
      for (int n = 0; n < NR; ++n)
        b[n] = *(const bf16x8*)&Bs[(wc * (BN / 2) + n * 16 + (lane & 15)) * BK + kb];
#pragma unroll
      for (int m = 0; m < MR; ++m)
#pragma unroll
        for (int n = 0; n < NR; ++n)
          acc[m][n] = __builtin_amdgcn_mfma_f32_16x16x32_bf16(a[m], b[n], acc[m][n], 0, 0, 0);
    }
  }

  // epilogue; C/D layout (m89-verified): col = lane&15, row = (lane>>4)*4 + j
  const int rbase = row0 + wr * (BM / 2), cbase = col0 + wc * (BN / 2);
#pragma unroll
  for (int m = 0; m < MR; ++m) {
#pragma unroll
    for (int n = 0; n < NR; ++n) {
      const int col = cbase + n * 16 + (lane & 15);
      const int r0q = rbase + m * 16 + ((lane >> 4) << 2);
#pragma unroll
      for (int j = 0; j < 4; ++j) {
        float v = acc[m][n][j];
        if (DO_RELU) {
          v = v > 0.f ? v : 0.f;
          ((ushort*)Cout)[(size_t)(r0q + j) * N + col] = f2bf(v);
        } else {
          ((float*)Cout)[(size_t)(r0q + j) * N + col] = v;
        }
      }
    }
  }
}

extern "C" void kernel_launch(void* const* d_in, const int* in_sizes, int n_in,
                              void* d_out, int out_size, void* d_ws, size_t ws_size,
                              hipStream_t stream) {
  const float* x  = (const float*)d_in[0];
  // d_in[1] (Wg) is provably unused: gating collapses to identity (see header)
  const float* w1 = (const float*)d_in[2];
  const float* w2 = (const float*)d_in[3];
  float* out = (float*)d_out;

  constexpr int S = 2048, D = 1024, F = 4096;
  char* ws = (char*)d_ws;
  ushort* xb  = (ushort*)(ws);                                    // [S][D]  4 MB
  ushort* w1t = (ushort*)(ws + (size_t)S * D * 2);                // [F][D]  8 MB
  ushort* w2t = (ushort*)(ws + (size_t)(S * D + F * D) * 2);      // [D][F]  8 MB
  ushort* H   = (ushort*)(ws + (size_t)(S * D + 2 * F * D) * 2);  // [S][F] 16 MB
  // fp32 split-K partial (8 MB) overlays xb + first half of w1t — both dead
  // once GEMM1 has consumed them.
  float* p1 = (float*)(ws);

  hipLaunchKernelGGL(cvt4, dim3((S * D / 4 + 255) / 256), dim3(256), 0, stream,
                     x, xb, S * D / 4);
  hipLaunchKernelGGL(transpose_cvt, dim3(F / 32, D / 32), dim3(32, 8), 0, stream,
                     w1, w1t, D, F);
  hipLaunchKernelGGL(transpose_cvt, dim3(D / 32, F / 32), dim3(32, 8), 0, stream,
                     w2, w2t, F, D);
  // GEMM1: H = relu(xb @ w1t^T)  [2048 x 4096], K=1024
  hipLaunchKernelGGL((gemm_bt<128, 128, 1>), dim3(F / 128, S / 128, 1), dim3(256), 0, stream,
                     xb, w1t, (void*)H, nullptr, S, F, D, D);
  // GEMM2: out = H @ w2t^T  [2048 x 1024], K=4096 split into 2x2048
  hipLaunchKernelGGL((gemm_bt<128, 64, 0>), dim3(D / 64, S / 128, 2), dim3(256), 0, stream,
                     H, w2t, (void*)out, (void*)p1, S, D, F / 2, F);
  // out += p1
  hipLaunchKernelGGL(add_partial, dim3((S * D / 4 + 255) / 256), dim3(256), 0, stream,
                     out, p1, S * D / 4);
}

// Round 3
// 91.365 us; speedup vs baseline: 1.2652x; 1.0630x over previous
//
#include <hip/hip_runtime.h>
#include <stdint.h>

// ============================================================================
// MoE collapses exactly to: out = relu(x @ w1) @ w2   (round-0 analysis)
//   - shared expert weights => both top-2 slots compute identical f(x[s])
//   - g1+g2 normalized to 1 => combine gather returns f(x[s])
//   - capacity = S and count1+count2 <= S => no token dropped
// Wg is unused.
//
// Round-2 -> 3: both GEMMs were latency-bound (MfmaUtil 13%, barrier drains
// HBM latency every K-step at 2 blocks/CU). This round: T3 minimum-2-phase
// double-buffered pipeline (stage NEXT tile before computing CURRENT tile;
// single barrier per K-step -> vmcnt drain overlaps MFMA). GEMM2 moves to
// 128x128 tile with split-K=4 (z=0 -> fp32 out, z=1..3 -> bf16 partials in
// dead ws region) + vectorized reduce.
// ============================================================================

typedef __attribute__((ext_vector_type(4))) float f32x4;
typedef __attribute__((ext_vector_type(8))) short bf16x8;

__device__ __forceinline__ ushort f2bf(float f) {
  uint32_t u = __float_as_uint(f);
  uint32_t r = (u + 0x7FFFu + ((u >> 16) & 1u)) >> 16;  // RNE
  return (ushort)r;
}
__device__ __forceinline__ float bf2f(ushort u) {
  return __uint_as_float((uint32_t)u << 16);
}

// ---- elementwise fp32 -> bf16, 4 elems/thread -------------------------------
__global__ void cvt4(const float* __restrict__ in, ushort* __restrict__ out, int n4) {
  int i = blockIdx.x * blockDim.x + threadIdx.x;
  if (i >= n4) return;
  float4 v = ((const float4*)in)[i];
  ushort4 o;
  o.x = f2bf(v.x); o.y = f2bf(v.y); o.z = f2bf(v.z); o.w = f2bf(v.w);
  ((ushort4*)out)[i] = o;
}

// ---- transpose + convert: in [R][C] fp32 -> out [C][R] bf16 -----------------
__global__ void transpose_cvt(const float* __restrict__ in, ushort* __restrict__ out,
                              int R, int C) {
  __shared__ float tile[32][33];
  const int c0 = blockIdx.x * 32, r0 = blockIdx.y * 32;
  const int tx = threadIdx.x, ty = threadIdx.y;  // blockDim (32,8)
#pragma unroll
  for (int i = 0; i < 32; i += 8)
    tile[ty + i][tx] = in[(size_t)(r0 + ty + i) * C + (c0 + tx)];
  __syncthreads();
#pragma unroll
  for (int i = 0; i < 32; i += 8)
    out[(size_t)(c0 + ty + i) * R + (r0 + tx)] = f2bf(tile[tx][ty + i]);
}

// ---- out += sum of 3 bf16 partials -----------------------------------------
__global__ void reduce_out(float* __restrict__ out, const ushort* __restrict__ pb,
                           int SD) {
  int i = blockIdx.x * blockDim.x + threadIdx.x;  // 4 floats / thread
  if (i >= SD / 4) return;
  f32x4 a = ((const f32x4*)out)[i];
#pragma unroll
  for (int j = 0; j < 3; ++j) {
    ushort4 u = ((const ushort4*)(pb + (size_t)j * SD))[i];
    a[0] += bf2f(u.x); a[1] += bf2f(u.y); a[2] += bf2f(u.z); a[3] += bf2f(u.w);
  }
  ((f32x4*)out)[i] = a;
}

// ---- bf16 GEMM, B transposed input ([N][K]), C = A@B ------------------------
// MODE 1: single output, relu -> bf16.
// MODE 2: split-K over blockIdx.z; z==0 -> fp32 C0, z>0 -> bf16 partial
//         C1 + (z-1)*M*N.
// 4 waves 2x2, per-wave (BM/2)x(BN/2), 16x16x32 bf16 MFMA, BK=64.
// 2-phase double-buffered LDS: stage(next) issued BEFORE compute(cur), one
// barrier per K-step (its vmcnt drain overlaps the MFMA phase).
template <int BM, int BN, int MODE>
__global__ __launch_bounds__(256) void gemm_bt(const ushort* __restrict__ A,
                                               const ushort* __restrict__ Bt,
                                               void* __restrict__ C0,
                                               void* __restrict__ C1,
                                               int M, int N, int Ks, int Ktot) {
  constexpr int BK = 64;
  __shared__ ushort As[2][BM * BK];
  __shared__ ushort Bs[2][BN * BK];
  constexpr int MR = BM / 32;  // 16x16 frags per wave along M
  constexpr int NR = BN / 32;
  constexpr int CA = BM / 8;   // 1-KB staging chunks for A tile
  constexpr int CB = BN / 8;
  constexpr int CPW = (CA + CB) / 4;

  const int tid = threadIdx.x;
  const int lane = tid & 63, wid = tid >> 6;
  const int wr = wid >> 1, wc = wid & 1;
  const int row0 = blockIdx.y * BM, col0 = blockIdx.x * BN;
  const int kbase = blockIdx.z * Ks;

  f32x4 acc[MR][NR];
#pragma unroll
  for (int m = 0; m < MR; ++m)
#pragma unroll
    for (int n = 0; n < NR; ++n) acc[m][n] = (f32x4){0.f, 0.f, 0.f, 0.f};

  auto stage = [&](int buf, int k0) {
#pragma unroll
    for (int i = 0; i < CPW; ++i) {
      int ci = wid * CPW + i;  // wave-uniform chunk id
      if (ci < CA) {
        int e = ci * 512 + lane * 8;  // bf16 element index
        int r = e >> 6, c = e & 63;
        __builtin_amdgcn_global_load_lds(
            (const __attribute__((address_space(1))) void*)(A + (size_t)(row0 + r) * Ktot + k0 + c),
            (__attribute__((address_space(3))) void*)(&As[buf][ci * 512]), 16, 0, 0);
      } else {
        int cj = ci - CA;
        int e = cj * 512 + lane * 8;
        int r = e >> 6, c = e & 63;
        __builtin_amdgcn_global_load_lds(
            (const __attribute__((address_space(1))) void*)(Bt + (size_t)(col0 + r) * Ktot + k0 + c),
            (__attribute__((address_space(3))) void*)(&Bs[buf][cj * 512]), 16, 0, 0);
      }
    }
  };

  auto compute = [&](int buf) {
#pragma unroll
    for (int kk = 0; kk < 2; ++kk) {
      const int kb = kk * 32 + (lane >> 4) * 8;
      bf16x8 a[MR], b[NR];
#pragma unroll
      for (int m = 0; m < MR; ++m)
        a[m] = *(const bf16x8*)&As[buf][(wr * (BM / 2) + m * 16 + (lane & 15)) * BK + kb];
#pragma unroll
      for (int n = 0; n < NR; ++n)
        b[n] = *(const bf16x8*)&Bs[buf][(wc * (BN / 2) + n * 16 + (lane & 15)) * BK + kb];
#pragma unroll
      for (int m = 0; m < MR; ++m)
#pragma unroll
        for (int n = 0; n < NR; ++n)
          acc[m][n] = __builtin_amdgcn_mfma_f32_16x16x32_bf16(a[m], b[n], acc[m][n], 0, 0, 0);
    }
  };

  const int nt = Ks / BK;
  stage(0, kbase);
  __syncthreads();  // drain prologue loads
  int cur = 0;
  for (int t = 0; t < nt; ++t) {
    if (t + 1 < nt) stage(cur ^ 1, kbase + (t + 1) * BK);  // loads fly over MFMA
    compute(cur);
    __syncthreads();  // next buf ready + cur buf reads done
    cur ^= 1;
  }

  // epilogue; C/D layout (m89-verified): col = lane&15, row = (lane>>4)*4 + j
  const int rbase = row0 + wr * (BM / 2), cbase = col0 + wc * (BN / 2);
#pragma unroll
  for (int m = 0; m < MR; ++m) {
#pragma unroll
    for (int n = 0; n < NR; ++n) {
      const int col = cbase + n * 16 + (lane & 15);
      const int r0q = rbase + m * 16 + ((lane >> 4) << 2);
#pragma unroll
      for (int j = 0; j < 4; ++j) {
        float v = acc[m][n][j];
        size_t idx = (size_t)(r0q + j) * N + col;
        if (MODE == 1) {
          v = v > 0.f ? v : 0.f;
          ((ushort*)C0)[idx] = f2bf(v);
        } else {
          if (blockIdx.z == 0)
            ((float*)C0)[idx] = v;
          else
            ((ushort*)C1)[(size_t)(blockIdx.z - 1) * M * N + idx] = f2bf(v);
        }
      }
    }
  }
}

extern "C" void kernel_launch(void* const* d_in, const int* in_sizes, int n_in,
                              void* d_out, int out_size, void* d_ws, size_t ws_size,
                              hipStream_t stream) {
  const float* x  = (const float*)d_in[0];
  // d_in[1] (Wg) is provably unused: gating collapses to identity (see header)
  const float* w1 = (const float*)d_in[2];
  const float* w2 = (const float*)d_in[3];
  float* out = (float*)d_out;

  constexpr int S = 2048, D = 1024, F = 4096;
  char* ws = (char*)d_ws;
  ushort* xb  = (ushort*)(ws);                                    // [S][D]  4 MB
  ushort* w1t = (ushort*)(ws + (size_t)S * D * 2);                // [F][D]  8 MB
  ushort* w2t = (ushort*)(ws + (size_t)(S * D + F * D) * 2);      // [D][F]  8 MB
  ushort* H   = (ushort*)(ws + (size_t)(S * D + 2 * F * D) * 2);  // [S][F] 16 MB
  // 3 bf16 split-K partials (12 MB) overlay xb (4 MB) + w1t (8 MB) — both
  // dead once GEMM1 has consumed them.
  ushort* pb = (ushort*)(ws);

  hipLaunchKernelGGL(cvt4, dim3((S * D / 4 + 255) / 256), dim3(256), 0, stream,
                     x, xb, S * D / 4);
  hipLaunchKernelGGL(transpose_cvt, dim3(F / 32, D / 32), dim3(32, 8), 0, stream,
                     w1, w1t, D, F);
  hipLaunchKernelGGL(transpose_cvt, dim3(D / 32, F / 32), dim3(32, 8), 0, stream,
                     w2, w2t, F, D);
  // GEMM1: H = relu(xb @ w1t^T)  [2048 x 4096], K=1024
  hipLaunchKernelGGL((gemm_bt<128, 128, 1>), dim3(F / 128, S / 128, 1), dim3(256), 0, stream,
                     xb, w1t, (void*)H, nullptr, S, F, D, D);
  // GEMM2: out = H @ w2t^T  [2048 x 1024], K=4096 split into 4x1024
  hipLaunchKernelGGL((gemm_bt<128, 128, 2>), dim3(D / 128, S / 128, 4), dim3(256), 0, stream,
                     H, w2t, (void*)out, (void*)pb, S, D, F / 4, F);
  // out += p1 + p2 + p3
  hipLaunchKernelGGL(reduce_out, dim3((S * D / 4 + 255) / 256), dim3(256), 0, stream,
                     out, pb, S * D);
}

// Round 4
// 79.894 us; speedup vs baseline: 1.4469x; 1.1436x over previous
//
#include <hip/hip_runtime.h>
#include <stdint.h>

// ============================================================================
// MoE collapses exactly to: out = relu(x @ w1) @ w2   (round-0 analysis)
//   - shared expert weights => both top-2 slots compute identical f(x[s])
//   - g1+g2 normalized to 1 => combine gather returns f(x[s])
//   - capacity = S and count1+count2 <= S => no token dropped
// Wg is unused.
//
// Round-3 -> 4: 2-phase dbuf hit the documented ~600TF 2-phase ceiling
// (vmcnt(0) drain inside __syncthreads each K-step). New structure:
//   T3+T4: triple-buffered LDS, depth-2 prefetch, counted s_waitcnt vmcnt(6)
//          + raw s_barrier (ONE barrier/K-step, never drain to 0 mid-loop)
//   T2:    XOR swizzle (row&7)<<4 on global source + ds_read addr
//          (linear global_load_lds dest, rule #21) -> kills 16-way conflict
//   T5:    s_setprio(1) around MFMA clusters
//   T1:    bijective XCD block swizzle (grid==256==8*32)
// Tile: BM=128 x BN=256 x BK=64, 8 waves (2x4), per-wave 64x64 (MR=NR=4).
// Grids: GEMM1 (16x16)=256 blocks; GEMM2 (4x16xz4)=256 blocks, Ks=1024.
// ============================================================================

typedef __attribute__((ext_vector_type(4))) float f32x4;
typedef __attribute__((ext_vector_type(8))) short bf16x8;

#define GPTR(p) (const __attribute__((address_space(1))) void*)(p)
#define LPTR(p) (__attribute__((address_space(3))) void*)(p)

__device__ __forceinline__ ushort f2bf(float f) {
  uint32_t u = __float_as_uint(f);
  uint32_t r = (u + 0x7FFFu + ((u >> 16) & 1u)) >> 16;  // RNE
  return (ushort)r;
}
__device__ __forceinline__ float bf2f(ushort u) {
  return __uint_as_float((uint32_t)u << 16);
}

// ---- elementwise fp32 -> bf16, 4 elems/thread -------------------------------
__global__ void cvt4(const float* __restrict__ in, ushort* __restrict__ out, int n4) {
  int i = blockIdx.x * blockDim.x + threadIdx.x;
  if (i >= n4) return;
  float4 v = ((const float4*)in)[i];
  ushort4 o;
  o.x = f2bf(v.x); o.y = f2bf(v.y); o.z = f2bf(v.z); o.w = f2bf(v.w);
  ((ushort4*)out)[i] = o;
}

// ---- transpose + convert: in [R][C] fp32 -> out [C][R] bf16 -----------------
__global__ void transpose_cvt(const float* __restrict__ in, ushort* __restrict__ out,
                              int R, int C) {
  __shared__ float tile[32][33];
  const int c0 = blockIdx.x * 32, r0 = blockIdx.y * 32;
  const int tx = threadIdx.x, ty = threadIdx.y;  // blockDim (32,8)
#pragma unroll
  for (int i = 0; i < 32; i += 8)
    tile[ty + i][tx] = in[(size_t)(r0 + ty + i) * C + (c0 + tx)];
  __syncthreads();
#pragma unroll
  for (int i = 0; i < 32; i += 8)
    out[(size_t)(c0 + ty + i) * R + (r0 + tx)] = f2bf(tile[tx][ty + i]);
}

// ---- out += sum of 3 bf16 partials -----------------------------------------
__global__ void reduce_out(float* __restrict__ out, const ushort* __restrict__ pb,
                           int SD) {
  int i = blockIdx.x * blockDim.x + threadIdx.x;  // 4 floats / thread
  if (i >= SD / 4) return;
  f32x4 a = ((const f32x4*)out)[i];
#pragma unroll
  for (int j = 0; j < 3; ++j) {
    ushort4 u = ((const ushort4*)(pb + (size_t)j * SD))[i];
    a[0] += bf2f(u.x); a[1] += bf2f(u.y); a[2] += bf2f(u.z); a[3] += bf2f(u.w);
  }
  ((f32x4*)out)[i] = a;
}

// ---- bf16 GEMM, B transposed ([N][K]); counted-vmcnt pipelined --------------
// MODE 1: C0 = relu(A@Bt^T) as bf16.  MODE 2: split-K; bz==0 -> fp32 C0,
// bz>0 -> bf16 partial C1 + (bz-1)*M*N.
template <int MODE>
__global__ __launch_bounds__(512) void gemm_pipe(const ushort* __restrict__ A,
                                                 const ushort* __restrict__ Bt,
                                                 void* __restrict__ C0,
                                                 void* __restrict__ C1,
                                                 int M, int N, int Ks, int Ktot,
                                                 int nx, int ny) {
  constexpr int BM = 128, BN = 256, BK = 64;
  __shared__ ushort As[3][BM * BK];  // 3 x 16 KB
  __shared__ ushort Bs[3][BN * BK];  // 3 x 32 KB   (total 144 KB)

  const int tid = threadIdx.x;
  const int lane = tid & 63, wid = tid >> 6;  // 8 waves
  const int wr = wid >> 2, wc = wid & 3;      // 2 x 4 wave grid

  // T1: bijective XCD swizzle (gridDim.x % 8 == 0 by construction)
  const int cpx = gridDim.x >> 3;
  const int swz = (blockIdx.x & 7) * cpx + (blockIdx.x >> 3);
  const int bx = swz % nx;
  const int by = (swz / nx) % ny;
  const int bz = swz / (nx * ny);
  const int row0 = by * BM, col0 = bx * BN;
  const int kbase = bz * Ks;

  f32x4 acc[4][4];
#pragma unroll
  for (int m = 0; m < 4; ++m)
#pragma unroll
    for (int n = 0; n < 4; ++n) acc[m][n] = (f32x4){0.f, 0.f, 0.f, 0.f};

  // stage tile t into buffer buf: 6 global_load_lds x 16B per thread.
  // LDS dest is LINEAR; source col is XOR-swizzled so that a ds_read at
  // swizzled addr returns logical data (rule #21: inverse-swz source).
  const int rA = tid >> 3;             // 0..63 row within an 8KB issue
  const int cb = (tid & 7) * 16;       // byte col within 128B row
  auto stage = [&](int buf, int k0) {
#pragma unroll
    for (int i = 0; i < 2; ++i) {      // A: 128 rows = 2 issues
      int r = i * 64 + rA;
      int csw = cb ^ ((r & 7) << 4);
      __builtin_amdgcn_global_load_lds(
          GPTR((const char*)(A + (size_t)(row0 + r) * Ktot + k0) + csw),
          LPTR((char*)&As[buf][0] + i * 8192 + wid * 1024), 16, 0, 0);
    }
#pragma unroll
    for (int j = 0; j < 4; ++j) {      // B: 256 rows = 4 issues
      int r = j * 64 + rA;
      int csw = cb ^ ((r & 7) << 4);
      __builtin_amdgcn_global_load_lds(
          GPTR((const char*)(Bt + (size_t)(col0 + r) * Ktot + k0) + csw),
          LPTR((char*)&Bs[buf][0] + j * 8192 + wid * 1024), 16, 0, 0);
    }
  };

  const int nt = Ks / BK;  // 16 for both GEMMs
  stage(0, kbase);
  stage(1, kbase + BK);

  for (int t = 0; t < nt; ++t) {
    // tile t resident for THIS wave; tile t+1's 6 loads stay in flight
    if (t < nt - 1) asm volatile("s_waitcnt vmcnt(6)" ::: "memory");
    else            asm volatile("s_waitcnt vmcnt(0)" ::: "memory");
    __builtin_amdgcn_sched_barrier(0);
    __builtin_amdgcn_s_barrier();   // all waves' tile-t loads landed; all
                                    // waves done reading buf[(t-1)%3]
    __builtin_amdgcn_sched_barrier(0);
    if (t + 2 < nt) stage((t + 2) % 3, kbase + (size_t)(t + 2) * BK);

    const ushort* Ab = As[t % 3];
    const ushort* Bb = Bs[t % 3];
#pragma unroll
    for (int kk = 0; kk < 2; ++kk) {
      const int kb2 = kk * 64 + (lane >> 4) * 16;  // k-slice byte offset
      bf16x8 a[4], b[4];
#pragma unroll
      for (int m = 0; m < 4; ++m) {
        int R = wr * 64 + m * 16 + (lane & 15);
        a[m] = *(const bf16x8*)((const char*)Ab + R * 128 + (kb2 ^ ((R & 7) << 4)));
      }
#pragma unroll
      for (int n = 0; n < 4; ++n) {
        int R = wc * 64 + n * 16 + (lane & 15);
        b[n] = *(const bf16x8*)((const char*)Bb + R * 128 + (kb2 ^ ((R & 7) << 4)));
      }
      __builtin_amdgcn_s_setprio(1);
#pragma unroll
      for (int m = 0; m < 4; ++m)
#pragma unroll
        for (int n = 0; n < 4; ++n)
          acc[m][n] = __builtin_amdgcn_mfma_f32_16x16x32_bf16(a[m], b[n], acc[m][n], 0, 0, 0);
      __builtin_amdgcn_s_setprio(0);
    }
  }

  // epilogue; C/D layout (m89-verified): col = lane&15, row = (lane>>4)*4 + j
  const int rbase = row0 + wr * 64, cbase = col0 + wc * 64;
#pragma unroll
  for (int m = 0; m < 4; ++m) {
#pragma unroll
    for (int n = 0; n < 4; ++n) {
      const int col = cbase + n * 16 + (lane & 15);
      const int r0q = rbase + m * 16 + ((lane >> 4) << 2);
#pragma unroll
      for (int j = 0; j < 4; ++j) {
        float v = acc[m][n][j];
        size_t idx = (size_t)(r0q + j) * N + col;
        if (MODE == 1) {
          v = v > 0.f ? v : 0.f;
          ((ushort*)C0)[idx] = f2bf(v);
        } else {
          if (bz == 0)
            ((float*)C0)[idx] = v;
          else
            ((ushort*)C1)[(size_t)(bz - 1) * M * N + idx] = f2bf(v);
        }
      }
    }
  }
}

extern "C" void kernel_launch(void* const* d_in, const int* in_sizes, int n_in,
                              void* d_out, int out_size, void* d_ws, size_t ws_size,
                              hipStream_t stream) {
  const float* x  = (const float*)d_in[0];
  // d_in[1] (Wg) is provably unused: gating collapses to identity (see header)
  const float* w1 = (const float*)d_in[2];
  const float* w2 = (const float*)d_in[3];
  float* out = (float*)d_out;

  constexpr int S = 2048, D = 1024, F = 4096;
  char* ws = (char*)d_ws;
  ushort* xb  = (ushort*)(ws);                                    // [S][D]  4 MB
  ushort* w1t = (ushort*)(ws + (size_t)S * D * 2);                // [F][D]  8 MB
  ushort* w2t = (ushort*)(ws + (size_t)(S * D + F * D) * 2);      // [D][F]  8 MB
  ushort* H   = (ushort*)(ws + (size_t)(S * D + 2 * F * D) * 2);  // [S][F] 16 MB
  // 3 bf16 split-K partials (12 MB) overlay xb+w1t (dead after GEMM1).
  ushort* pb = (ushort*)(ws);

  hipLaunchKernelGGL(cvt4, dim3((S * D / 4 + 255) / 256), dim3(256), 0, stream,
                     x, xb, S * D / 4);
  hipLaunchKernelGGL(transpose_cvt, dim3(F / 32, D / 32), dim3(32, 8), 0, stream,
                     w1, w1t, D, F);
  hipLaunchKernelGGL(transpose_cvt, dim3(D / 32, F / 32), dim3(32, 8), 0, stream,
                     w2, w2t, F, D);
  // GEMM1: H = relu(xb @ w1t^T)  [2048 x 4096], K=1024; grid 16x16 = 256
  hipLaunchKernelGGL((gemm_pipe<1>), dim3(256), dim3(512), 0, stream,
                     xb, w1t, (void*)H, nullptr, S, F, D, D, F / 256, S / 128);
  // GEMM2: out = H @ w2t^T  [2048 x 1024], K=4096 split 4x1024; grid 4x16x4 = 256
  hipLaunchKernelGGL((gemm_pipe<2>), dim3(256), dim3(512), 0, stream,
                     H, w2t, (void*)out, (void*)pb, S, D, F / 4, F, D / 256, S / 128);
  // out += p1 + p2 + p3
  hipLaunchKernelGGL(reduce_out, dim3((S * D / 4 + 255) / 256), dim3(256), 0, stream,
                     out, pb, S * D);
}

// Round 5
// 74.896 us; speedup vs baseline: 1.5434x; 1.0667x over previous
//
#include <hip/hip_runtime.h>
#include <stdint.h>

// ============================================================================
// MoE collapses exactly to: out = relu(x @ w1) @ w2   (round-0 analysis)
//   - shared expert weights => both top-2 slots compute identical f(x[s])
//   - g1+g2 normalized to 1 => combine gather returns f(x[s])
//   - capacity = S and count1+count2 <= S => no token dropped
// Wg is unused.
//
// Round-4 -> 5 (pipeline/sync structure UNCHANGED — verified last round):
//   * 16x16x32 -> 32x32x16 MFMA (same ds_read count, ~12% less MFMA-pipe
//     time, half the MFMA instruction overhead)
//   * 2D-chunked XCD swizzle: each XCD owns a 4(bx) x 8(by) sub-grid ->
//     per-XCD operand re-fetch drops (GEMM1 FETCH ~70 -> ~36 MB)
//   * prep (cvt + 2 transposes) fused into ONE kernel (concurrent, -2 launches)
// Tile: BM=128 x BN=256 x BK=64, 8 waves (2x4), per-wave 64x64 (2x2 32x32).
// ============================================================================

typedef __attribute__((ext_vector_type(4))) float f32x4;
typedef __attribute__((ext_vector_type(16))) float f32x16;
typedef __attribute__((ext_vector_type(8))) short bf16x8;

#define GPTR(p) (const __attribute__((address_space(1))) void*)(p)
#define LPTR(p) (__attribute__((address_space(3))) void*)(p)

__device__ __forceinline__ ushort f2bf(float f) {
  uint32_t u = __float_as_uint(f);
  uint32_t r = (u + 0x7FFFu + ((u >> 16) & 1u)) >> 16;  // RNE
  return (ushort)r;
}
__device__ __forceinline__ float bf2f(ushort u) {
  return __uint_as_float((uint32_t)u << 16);
}

// ---- fused prep: x->bf16, w1->w1t (bf16, transposed), w2->w2t ---------------
// grid: [0,2048) cvt4 of x; [2048,6144) transpose w1; [6144,10240) transpose w2
__device__ __forceinline__ void tile_transpose(const float* __restrict__ in,
                                               ushort* __restrict__ out,
                                               int R, int C, int bx, int by,
                                               int tx, int ty) {
  __shared__ float tile[32][33];
  const int c0 = bx * 32, r0 = by * 32;
#pragma unroll
  for (int i = 0; i < 32; i += 8)
    tile[ty + i][tx] = in[(size_t)(r0 + ty + i) * C + (c0 + tx)];
  __syncthreads();
#pragma unroll
  for (int i = 0; i < 32; i += 8)
    out[(size_t)(c0 + ty + i) * R + (r0 + tx)] = f2bf(tile[tx][ty + i]);
}

__global__ void prep(const float* __restrict__ x, const float* __restrict__ w1,
                     const float* __restrict__ w2, ushort* __restrict__ xb,
                     ushort* __restrict__ w1t, ushort* __restrict__ w2t) {
  const int b = blockIdx.x;
  const int tx = threadIdx.x, ty = threadIdx.y;  // (32,8)
  if (b < 2048) {  // cvt: 2048*256 threads * 4 elems = 2M = S*D
    int i = b * 256 + ty * 32 + tx;
    float4 v = ((const float4*)x)[i];
    ushort4 o;
    o.x = f2bf(v.x); o.y = f2bf(v.y); o.z = f2bf(v.z); o.w = f2bf(v.w);
    ((ushort4*)xb)[i] = o;
  } else if (b < 6144) {  // w1 [1024][4096] -> w1t [4096][1024]
    int b2 = b - 2048;
    tile_transpose(w1, w1t, 1024, 4096, b2 & 127, b2 >> 7, tx, ty);
  } else {  // w2 [4096][1024] -> w2t [1024][4096]
    int b3 = b - 6144;
    tile_transpose(w2, w2t, 4096, 1024, b3 & 31, b3 >> 5, tx, ty);
  }
}

// ---- out += sum of 3 bf16 partials -----------------------------------------
__global__ void reduce_out(float* __restrict__ out, const ushort* __restrict__ pb,
                           int SD) {
  int i = blockIdx.x * blockDim.x + threadIdx.x;  // 4 floats / thread
  if (i >= SD / 4) return;
  f32x4 a = ((const f32x4*)out)[i];
#pragma unroll
  for (int j = 0; j < 3; ++j) {
    ushort4 u = ((const ushort4*)(pb + (size_t)j * SD))[i];
    a[0] += bf2f(u.x); a[1] += bf2f(u.y); a[2] += bf2f(u.z); a[3] += bf2f(u.w);
  }
  ((f32x4*)out)[i] = a;
}

// ---- bf16 GEMM, B transposed ([N][K]); counted-vmcnt pipelined --------------
// MODE 1: C0 = relu(A@Bt^T) as bf16.  MODE 2: split-K; bz==0 -> fp32 C0,
// bz>0 -> bf16 partial C1 + (bz-1)*M*N.
// XCD 2D chunking: chunk (=XCD) covers 4(bx) x 8(by); chunk grid is
// ncx wide in x, (ny/8) tall, cpz = ncx*(ny/8) chunks per K-slice.
template <int MODE>
__global__ __launch_bounds__(512) void gemm_pipe(const ushort* __restrict__ A,
                                                 const ushort* __restrict__ Bt,
                                                 void* __restrict__ C0,
                                                 void* __restrict__ C1,
                                                 int M, int N, int Ks, int Ktot,
                                                 int ncx, int cpz) {
  constexpr int BM = 128, BN = 256, BK = 64;
  __shared__ ushort As[3][BM * BK];  // 3 x 16 KB
  __shared__ ushort Bs[3][BN * BK];  // 3 x 32 KB   (total 144 KB)

  const int tid = threadIdx.x;
  const int lane = tid & 63, wid = tid >> 6;  // 8 waves
  const int wr = wid >> 2, wc = wid & 3;      // 2 x 4 wave grid

  // T1 (2D-chunked): chunk index = blockIdx.x & 7 (round-robin XCD),
  // position within chunk = blockIdx.x >> 3 (0..31 -> 4 x 8).
  const int ck = blockIdx.x & 7;
  const int w = blockIdx.x >> 3;
  const int bz = ck / cpz;
  const int rem = ck % cpz;
  const int bx = (rem % ncx) * 4 + (w & 3);
  const int by = (rem / ncx) * 8 + (w >> 2);
  const int row0 = by * BM, col0 = bx * BN;
  const int kbase = bz * Ks;

  f32x16 acc[2][2];
#pragma unroll
  for (int m = 0; m < 2; ++m)
#pragma unroll
    for (int n = 0; n < 2; ++n) acc[m][n] = (f32x16)(0.f);

  // stage tile t into buffer buf: 6 global_load_lds x 16B per thread.
  // LDS dest is LINEAR; source col is XOR-swizzled (rule #21) so the
  // swizzled ds_read below returns logical data. (verified rounds 4)
  const int rA = tid >> 3;             // 0..63 row within an 8KB issue
  const int cb = (tid & 7) * 16;       // byte col within 128B row
  auto stage = [&](int buf, int k0) {
#pragma unroll
    for (int i = 0; i < 2; ++i) {      // A: 128 rows = 2 issues
      int r = i * 64 + rA;
      int csw = cb ^ ((r & 7) << 4);
      __builtin_amdgcn_global_load_lds(
          GPTR((const char*)(A + (size_t)(row0 + r) * Ktot + k0) + csw),
          LPTR((char*)&As[buf][0] + i * 8192 + wid * 1024), 16, 0, 0);
    }
#pragma unroll
    for (int j = 0; j < 4; ++j) {      // B: 256 rows = 4 issues
      int r = j * 64 + rA;
      int csw = cb ^ ((r & 7) << 4);
      __builtin_amdgcn_global_load_lds(
          GPTR((const char*)(Bt + (size_t)(col0 + r) * Ktot + k0) + csw),
          LPTR((char*)&Bs[buf][0] + j * 8192 + wid * 1024), 16, 0, 0);
    }
  };

  const int nt = Ks / BK;  // 16 for both GEMMs
  stage(0, kbase);
  stage(1, kbase + BK);

  for (int t = 0; t < nt; ++t) {
    // tile t resident for THIS wave; tile t+1's 6 loads stay in flight
    if (t < nt - 1) asm volatile("s_waitcnt vmcnt(6)" ::: "memory");
    else            asm volatile("s_waitcnt vmcnt(0)" ::: "memory");
    __builtin_amdgcn_sched_barrier(0);
    __builtin_amdgcn_s_barrier();   // all waves' tile-t loads landed; all
                                    // waves done reading buf[(t-1)%3]
    __builtin_amdgcn_sched_barrier(0);
    if (t + 2 < nt) stage((t + 2) % 3, kbase + (size_t)(t + 2) * BK);

    const ushort* Ab = As[t % 3];
    const ushort* Bb = Bs[t % 3];
    // 32x32x16: A-frag lane holds row=lane&31, k=(lane>>5)*8+j; BK=64 -> 4
    // k-slices of 16. Byte-in-row = s*32 + (lane>>5)*16, XOR row swizzle.
#pragma unroll
    for (int s = 0; s < 4; ++s) {
      const int kb2 = s * 32 + (lane >> 5) * 16;
      bf16x8 a[2], b[2];
#pragma unroll
      for (int m = 0; m < 2; ++m) {
        int R = wr * 64 + m * 32 + (lane & 31);
        a[m] = *(const bf16x8*)((const char*)Ab + R * 128 + (kb2 ^ ((R & 7) << 4)));
      }
#pragma unroll
      for (int n = 0; n < 2; ++n) {
        int R = wc * 64 + n * 32 + (lane & 31);
        b[n] = *(const bf16x8*)((const char*)Bb + R * 128 + (kb2 ^ ((R & 7) << 4)));
      }
      __builtin_amdgcn_s_setprio(1);
#pragma unroll
      for (int m = 0; m < 2; ++m)
#pragma unroll
        for (int n = 0; n < 2; ++n)
          acc[m][n] = __builtin_amdgcn_mfma_f32_32x32x16_bf16(a[m], b[n], acc[m][n], 0, 0, 0);
      __builtin_amdgcn_s_setprio(0);
    }
  }

  // epilogue; 32x32 C/D layout (m74/m101-verified):
  //   col = lane&31, row = (r&3) + 8*(r>>2) + 4*(lane>>5)
  const int rbase = row0 + wr * 64, cbase = col0 + wc * 64;
#pragma unroll
  for (int m = 0; m < 2; ++m) {
#pragma unroll
    for (int n = 0; n < 2; ++n) {
      const int col = cbase + n * 32 + (lane & 31);
#pragma unroll
      for (int r = 0; r < 16; ++r) {
        const int row = rbase + m * 32 + (r & 3) + 8 * (r >> 2) + 4 * (lane >> 5);
        float v = acc[m][n][r];
        size_t idx = (size_t)row * N + col;
        if (MODE == 1) {
          v = v > 0.f ? v : 0.f;
          ((ushort*)C0)[idx] = f2bf(v);
        } else {
          if (bz == 0)
            ((float*)C0)[idx] = v;
          else
            ((ushort*)C1)[(size_t)(bz - 1) * M * N + idx] = f2bf(v);
        }
      }
    }
  }
}

extern "C" void kernel_launch(void* const* d_in, const int* in_sizes, int n_in,
                              void* d_out, int out_size, void* d_ws, size_t ws_size,
                              hipStream_t stream) {
  const float* x  = (const float*)d_in[0];
  // d_in[1] (Wg) is provably unused: gating collapses to identity (see header)
  const float* w1 = (const float*)d_in[2];
  const float* w2 = (const float*)d_in[3];
  float* out = (float*)d_out;

  constexpr int S = 2048, D = 1024, F = 4096;
  char* ws = (char*)d_ws;
  ushort* xb  = (ushort*)(ws);                                    // [S][D]  4 MB
  ushort* w1t = (ushort*)(ws + (size_t)S * D * 2);                // [F][D]  8 MB
  ushort* w2t = (ushort*)(ws + (size_t)(S * D + F * D) * 2);      // [D][F]  8 MB
  ushort* H   = (ushort*)(ws + (size_t)(S * D + 2 * F * D) * 2);  // [S][F] 16 MB
  // 3 bf16 split-K partials (12 MB) overlay xb+w1t (dead after GEMM1).
  ushort* pb = (ushort*)(ws);

  // fused prep: 2048 cvt blocks + 4096 w1-transpose + 4096 w2-transpose
  hipLaunchKernelGGL(prep, dim3(10240), dim3(32, 8), 0, stream,
                     x, w1, w2, xb, w1t, w2t);
  // GEMM1: H = relu(xb @ w1t^T)  [2048 x 4096], K=1024
  //   grid 16x16 = 256; chunk grid: ncx=4, cpz=8 (nz=1)
  hipLaunchKernelGGL((gemm_pipe<1>), dim3(256), dim3(512), 0, stream,
                     xb, w1t, (void*)H, nullptr, S, F, D, D, 4, 8);
  // GEMM2: out = H @ w2t^T  [2048 x 1024], K=4096 split 4x1024
  //   grid 4x16x4 = 256; chunk grid: ncx=1, cpz=2 (nz=4)
  hipLaunchKernelGGL((gemm_pipe<2>), dim3(256), dim3(512), 0, stream,
                     H, w2t, (void*)out, (void*)pb, S, D, F / 4, F, 1, 2);
  // out += p1 + p2 + p3
  hipLaunchKernelGGL(reduce_out, dim3((S * D / 4 + 255) / 256), dim3(256), 0, stream,
                     out, pb, S * D);
}